// Round 2
// baseline (501.492 us; speedup 1.0000x reference)
//
#include <hip/hip_runtime.h>
#include <math.h>

#define D_DIM 128
#define A_DIM 128
#define BM 128            // rows per block tile
#define NTHREADS 512      // 8 waves

typedef __attribute__((ext_vector_type(8))) short bf16x8;
typedef __attribute__((ext_vector_type(4))) float f32x4;

__device__ __forceinline__ float fast_tanh(float v) {
    float e = __expf(2.0f * v);
    return 1.0f - 2.0f * __builtin_amdgcn_rcpf(e + 1.0f);
}

__device__ __forceinline__ void split_bf16(float x, short& hi, short& lo) {
    unsigned u = __float_as_uint(x);
    hi = (short)(u >> 16);                         // truncated bf16 hi
    float hf = __uint_as_float(u & 0xffff0000u);
    float lf = x - hf;                             // residual, |lf| <= 2^-8 |x|
    lo = (short)(__float_as_uint(lf) >> 16);       // truncated bf16 lo
}

// K1: scores[i] = sum_a tanh( dot(x_i, W1[:,a]) + b1[a] ) * W2[a]
// split-bf16 MFMA (hi*hi + hi*lo + lo*hi), b2 cancels in softmax.
extern "C" __global__ void __launch_bounds__(NTHREADS, 4)
scores_mfma_kernel(const float* __restrict__ x,
                   const float* __restrict__ W1,
                   const float* __restrict__ b1,
                   const float* __restrict__ W2,
                   float* __restrict__ scores,
                   int N, int numTiles)
{
    // W1 transposed [col][k], split hi/lo bf16, XOR-swizzled 16B chunks.
    // Exactly 64 KB total -> 2 blocks/CU.
    __shared__ short w1h[A_DIM * D_DIM];
    __shared__ short w1l[A_DIM * D_DIM];

    const int tid = threadIdx.x;

    // ---- stage W1: read coalesced [k][c], write transposed+swizzled ----
    // item = chunk*128 + c ; chunk = 16B = 8 consecutive k for column c
    for (int item = tid; item < A_DIM * 16; item += NTHREADS) {
        const int c = item & (A_DIM - 1);
        const int chunk = item >> 7;          // 0..15 over 4 iterations
        bf16x8 vh, vl;
        #pragma unroll
        for (int j = 0; j < 8; ++j) {
            float v = W1[(chunk * 8 + j) * A_DIM + c];   // coalesced in c
            short h, l; split_bf16(v, h, l);
            vh[j] = h; vl[j] = l;
        }
        const int addr = c * 256 + ((chunk ^ (c & 15)) << 4);   // byte offset
        *reinterpret_cast<bf16x8*>(reinterpret_cast<char*>(w1h) + addr) = vh;
        *reinterpret_cast<bf16x8*>(reinterpret_cast<char*>(w1l) + addr) = vl;
    }
    __syncthreads();

    const int lane = tid & 63;
    const int wv   = tid >> 6;          // wave 0..7 -> rows wv*16..wv*16+15
    const int lc   = lane & 15;         // A-row / B-col / C-col within tile
    const int lg   = lane >> 4;         // 0..3

    // per-lane bias/W2 for cols 16t+lc
    float b1r[8], w2r[8];
    #pragma unroll
    for (int t = 0; t < 8; ++t) {
        b1r[t] = b1[t * 16 + lc];
        w2r[t] = W2[t * 16 + lc];
    }

    for (int tile = blockIdx.x; tile < numTiles; tile += gridDim.x) {
        const int row  = tile * BM + wv * 16 + lc;
        const int rowc = min(row, N - 1);
        const float* xr = x + (size_t)rowc * D_DIM;

        // A-fragments: rows of x, split hi/lo. k = ks*32 + lg*8 + j
        bf16x8 ah[4], al[4];
        #pragma unroll
        for (int ks = 0; ks < 4; ++ks) {
            const float4* p = reinterpret_cast<const float4*>(xr + ks * 32 + lg * 8);
            float4 v0 = p[0], v1 = p[1];
            float vv[8] = {v0.x, v0.y, v0.z, v0.w, v1.x, v1.y, v1.z, v1.w};
            #pragma unroll
            for (int j = 0; j < 8; ++j) {
                short h, l; split_bf16(vv[j], h, l);
                ah[ks][j] = h; al[ks][j] = l;
            }
        }

        float part0 = 0.f, part1 = 0.f, part2 = 0.f, part3 = 0.f;
        #pragma unroll
        for (int t = 0; t < 8; ++t) {
            f32x4 acc = {0.f, 0.f, 0.f, 0.f};
            const int c = t * 16 + lc;
            #pragma unroll
            for (int ks = 0; ks < 4; ++ks) {
                const int chunk = ks * 4 + lg;
                const int addr = c * 256 + ((chunk ^ (c & 15)) << 4);
                bf16x8 bh = *reinterpret_cast<const bf16x8*>(
                    reinterpret_cast<const char*>(w1h) + addr);
                bf16x8 bl = *reinterpret_cast<const bf16x8*>(
                    reinterpret_cast<const char*>(w1l) + addr);
                acc = __builtin_amdgcn_mfma_f32_16x16x32_bf16(ah[ks], bh, acc, 0, 0, 0);
                acc = __builtin_amdgcn_mfma_f32_16x16x32_bf16(al[ks], bh, acc, 0, 0, 0);
                acc = __builtin_amdgcn_mfma_f32_16x16x32_bf16(ah[ks], bl, acc, 0, 0, 0);
            }
            // C layout: col = lane&15 (= c), row = lg*4 + reg
            const float b1v = b1r[t], w2v = w2r[t];
            part0 += fast_tanh(acc[0] + b1v) * w2v;
            part1 += fast_tanh(acc[1] + b1v) * w2v;
            part2 += fast_tanh(acc[2] + b1v) * w2v;
            part3 += fast_tanh(acc[3] + b1v) * w2v;
        }
        // sum over the 16 lanes sharing lg (they hold disjoint col ranges)
        #pragma unroll
        for (int m = 8; m >= 1; m >>= 1) {
            part0 += __shfl_xor(part0, m);
            part1 += __shfl_xor(part1, m);
            part2 += __shfl_xor(part2, m);
            part3 += __shfl_xor(part3, m);
        }
        if (lc == 0) {
            const int rbase = tile * BM + wv * 16 + lg * 4;
            if (rbase + 0 < N) scores[rbase + 0] = part0;
            if (rbase + 1 < N) scores[rbase + 1] = part1;
            if (rbase + 2 < N) scores[rbase + 2] = part2;
            if (rbase + 3 < N) scores[rbase + 3] = part3;
        }
    }
}

__device__ __forceinline__ int lower_bound_i32(const int* __restrict__ arr, int n, int val) {
    int lo = 0, hi = n;
    while (lo < hi) {
        int mid = (lo + hi) >> 1;
        if (arr[mid] < val) lo = mid + 1; else hi = mid;
    }
    return lo;
}

// K2: per-segment max and sum(exp(s-max)); also record segment bounds
extern "C" __global__ void __launch_bounds__(256)
segstats_kernel(const float* __restrict__ scores, const int* __restrict__ bidx,
                int N, float* __restrict__ seg_max, float* __restrict__ seg_denom,
                int* __restrict__ seg_start)
{
    const int b = blockIdx.x;
    const int lo = lower_bound_i32(bidx, N, b);
    const int hi = lower_bound_i32(bidx, N, b + 1);
    if (threadIdx.x == 0) {
        seg_start[b] = lo;
        if (b == (int)gridDim.x - 1) seg_start[b + 1] = hi;  // == N
    }

    __shared__ float red[256];
    float m = -INFINITY;
    for (int i = lo + threadIdx.x; i < hi; i += 256) m = fmaxf(m, scores[i]);
    red[threadIdx.x] = m;
    __syncthreads();
    #pragma unroll
    for (int off = 128; off > 0; off >>= 1) {
        if (threadIdx.x < off) red[threadIdx.x] = fmaxf(red[threadIdx.x], red[threadIdx.x + off]);
        __syncthreads();
    }
    m = red[0];
    __syncthreads();

    float sum = 0.0f;
    for (int i = lo + threadIdx.x; i < hi; i += 256) sum += __expf(scores[i] - m);
    red[threadIdx.x] = sum;
    __syncthreads();
    #pragma unroll
    for (int off = 128; off > 0; off >>= 1) {
        if (threadIdx.x < off) red[threadIdx.x] += red[threadIdx.x + off];
        __syncthreads();
    }
    if (threadIdx.x == 0) { seg_max[b] = m; seg_denom[b] = red[0]; }
}

// K3: out[b][d] = sum_{i in seg b} (exp(s_i - max_b)/denom_b) * x[i][d]
extern "C" __global__ void __launch_bounds__(128)
weighted_sum_kernel(const float* __restrict__ x, const float* __restrict__ scores,
                    const float* __restrict__ seg_max, const float* __restrict__ seg_denom,
                    const int* __restrict__ seg_start, float* __restrict__ out,
                    int chunks)
{
    const int b = blockIdx.x;
    const int c = blockIdx.y;
    const int lo = seg_start[b], hi = seg_start[b + 1];
    const int len = hi - lo;
    if (len <= 0) return;
    const int per = (len + chunks - 1) / chunks;
    const int s0 = lo + c * per;
    const int s1 = min(hi, s0 + per);
    if (s0 >= s1) return;

    const float m = seg_max[b];
    const float inv_den = 1.0f / seg_denom[b];
    const int d = threadIdx.x;

    float acc = 0.0f;
    #pragma unroll 4
    for (int i = s0; i < s1; ++i) {
        float w = __expf(scores[i] - m) * inv_den;
        acc = fmaf(w, x[(size_t)i * D_DIM + d], acc);
    }
    atomicAdd(&out[b * D_DIM + d], acc);
}

extern "C" void kernel_launch(void* const* d_in, const int* in_sizes, int n_in,
                              void* d_out, int out_size, void* d_ws, size_t ws_size,
                              hipStream_t stream)
{
    const float* x    = (const float*)d_in[0];
    const int*   bidx = (const int*)d_in[1];
    const float* W1   = (const float*)d_in[2];
    const float* b1   = (const float*)d_in[3];
    const float* W2   = (const float*)d_in[4];
    // d_in[5] = b2: cancels in softmax, unused

    const int N = in_sizes[1];
    const int B = out_size / D_DIM;

    float* out = (float*)d_out;
    char* ws = (char*)d_ws;
    float* scores    = (float*)ws;  // N floats
    size_t off = ((size_t)N * sizeof(float) + 255) & ~(size_t)255;
    float* seg_max   = (float*)(ws + off);
    float* seg_denom = seg_max + B;
    int*   seg_start = (int*)(seg_denom + B);  // B+1 ints

    hipMemsetAsync(d_out, 0, (size_t)out_size * sizeof(float), stream);

    const int numTiles = (N + BM - 1) / BM;
    const int grid1 = numTiles < 1024 ? numTiles : 1024;
    scores_mfma_kernel<<<grid1, NTHREADS, 0, stream>>>(x, W1, b1, W2, scores, N, numTiles);
    segstats_kernel<<<B, 256, 0, stream>>>(scores, bidx, N, seg_max, seg_denom, seg_start);
    const int chunks = 8;
    weighted_sum_kernel<<<dim3(B, chunks), 128, 0, stream>>>(
        x, scores, seg_max, seg_denom, seg_start, out, chunks);
}

// Round 3
// 252.267 us; speedup vs baseline: 1.9879x; 1.9879x over previous
//
#include <hip/hip_runtime.h>
#include <math.h>

#define D_DIM 128
#define A_DIM 128
#define BM 128            // rows per block tile
#define NTHREADS 512      // 8 waves

typedef __attribute__((ext_vector_type(8))) short bf16x8;
typedef __attribute__((ext_vector_type(4))) float f32x4;

__device__ __forceinline__ float fast_tanh(float v) {
    float e = __expf(2.0f * v);
    return 1.0f - 2.0f * __builtin_amdgcn_rcpf(e + 1.0f);
}

__device__ __forceinline__ void split_bf16(float x, short& hi, short& lo) {
    unsigned u = __float_as_uint(x);
    hi = (short)(u >> 16);                         // truncated bf16 hi
    float hf = __uint_as_float(u & 0xffff0000u);
    float lf = x - hf;                             // residual, |lf| <= 2^-8 |x|
    lo = (short)(__float_as_uint(lf) >> 16);       // truncated bf16 lo
}

// K1: scores[i] = sum_a tanh( dot(x_i, W1[:,a]) + b1[a] ) * W2[a]
// split-bf16 MFMA (hi*hi + hi*lo + lo*hi), b2 cancels in softmax.
// NOTE: no waves-per-EU hint — R1's (512,4) forced a 64-VGPR allocation and
// the ~90 live regs spilled to scratch (434 MB WRITE_SIZE, 4x FETCH, 447us).
extern "C" __global__ void __launch_bounds__(NTHREADS)
scores_mfma_kernel(const float* __restrict__ x,
                   const float* __restrict__ W1,
                   const float* __restrict__ b1,
                   const float* __restrict__ W2,
                   float* __restrict__ scores,
                   int N, int numTiles)
{
    // W1 transposed [col][k], split hi/lo bf16, XOR-swizzled 16B chunks.
    __shared__ short w1h[A_DIM * D_DIM];
    __shared__ short w1l[A_DIM * D_DIM];
    __shared__ float sB1[A_DIM];
    __shared__ float sW2[A_DIM];

    const int tid = threadIdx.x;

    if (tid < A_DIM) { sB1[tid] = b1[tid]; sW2[tid] = W2[tid]; }

    // ---- stage W1: read coalesced [k][c], write transposed+swizzled ----
    for (int item = tid; item < A_DIM * 16; item += NTHREADS) {
        const int c = item & (A_DIM - 1);
        const int chunk = item >> 7;          // 16B chunk index along k
        bf16x8 vh, vl;
        #pragma unroll
        for (int j = 0; j < 8; ++j) {
            float v = W1[(chunk * 8 + j) * A_DIM + c];   // coalesced in c
            short h, l; split_bf16(v, h, l);
            vh[j] = h; vl[j] = l;
        }
        const int addr = c * 256 + ((chunk ^ (c & 15)) << 4);   // byte offset
        *reinterpret_cast<bf16x8*>(reinterpret_cast<char*>(w1h) + addr) = vh;
        *reinterpret_cast<bf16x8*>(reinterpret_cast<char*>(w1l) + addr) = vl;
    }
    __syncthreads();

    const int lane = tid & 63;
    const int wv   = tid >> 6;          // wave 0..7 -> rows wv*16..wv*16+15
    const int lc   = lane & 15;         // A-row / C-col within tile
    const int lg   = lane >> 4;         // 0..3

    for (int tile = blockIdx.x; tile < numTiles; tile += gridDim.x) {
        const int row  = tile * BM + wv * 16 + lc;
        const int rowc = min(row, N - 1);
        const float* xr = x + (size_t)rowc * D_DIM;

        // A-fragments: rows of x, split hi/lo. k = ks*32 + lg*8 + j
        bf16x8 ah[4], al[4];
        #pragma unroll
        for (int ks = 0; ks < 4; ++ks) {
            const float4* p = reinterpret_cast<const float4*>(xr + ks * 32 + lg * 8);
            float4 v0 = p[0], v1 = p[1];
            short h, l;
            split_bf16(v0.x, h, l); ah[ks][0] = h; al[ks][0] = l;
            split_bf16(v0.y, h, l); ah[ks][1] = h; al[ks][1] = l;
            split_bf16(v0.z, h, l); ah[ks][2] = h; al[ks][2] = l;
            split_bf16(v0.w, h, l); ah[ks][3] = h; al[ks][3] = l;
            split_bf16(v1.x, h, l); ah[ks][4] = h; al[ks][4] = l;
            split_bf16(v1.y, h, l); ah[ks][5] = h; al[ks][5] = l;
            split_bf16(v1.z, h, l); ah[ks][6] = h; al[ks][6] = l;
            split_bf16(v1.w, h, l); ah[ks][7] = h; al[ks][7] = l;
        }

        float part0 = 0.f, part1 = 0.f, part2 = 0.f, part3 = 0.f;
        #pragma unroll
        for (int t = 0; t < 8; ++t) {
            f32x4 acc = {0.f, 0.f, 0.f, 0.f};
            const int c = t * 16 + lc;
            #pragma unroll
            for (int ks = 0; ks < 4; ++ks) {
                const int chunk = ks * 4 + lg;
                const int addr = c * 256 + ((chunk ^ (c & 15)) << 4);
                bf16x8 bh = *reinterpret_cast<const bf16x8*>(
                    reinterpret_cast<const char*>(w1h) + addr);
                bf16x8 bl = *reinterpret_cast<const bf16x8*>(
                    reinterpret_cast<const char*>(w1l) + addr);
                acc = __builtin_amdgcn_mfma_f32_16x16x32_bf16(ah[ks], bh, acc, 0, 0, 0);
                acc = __builtin_amdgcn_mfma_f32_16x16x32_bf16(al[ks], bh, acc, 0, 0, 0);
                acc = __builtin_amdgcn_mfma_f32_16x16x32_bf16(ah[ks], bl, acc, 0, 0, 0);
            }
            // C layout: col = lane&15 (= c), row = lg*4 + reg
            const float b1v = sB1[c], w2v = sW2[c];   // uniform-ish LDS broadcast
            part0 += fast_tanh(acc[0] + b1v) * w2v;
            part1 += fast_tanh(acc[1] + b1v) * w2v;
            part2 += fast_tanh(acc[2] + b1v) * w2v;
            part3 += fast_tanh(acc[3] + b1v) * w2v;
        }
        // sum over the 16 lanes sharing lg (they hold disjoint col ranges)
        #pragma unroll
        for (int m = 8; m >= 1; m >>= 1) {
            part0 += __shfl_xor(part0, m);
            part1 += __shfl_xor(part1, m);
            part2 += __shfl_xor(part2, m);
            part3 += __shfl_xor(part3, m);
        }
        if (lc == 0) {
            const int rbase = tile * BM + wv * 16 + lg * 4;
            if (rbase + 0 < N) scores[rbase + 0] = part0;
            if (rbase + 1 < N) scores[rbase + 1] = part1;
            if (rbase + 2 < N) scores[rbase + 2] = part2;
            if (rbase + 3 < N) scores[rbase + 3] = part3;
        }
    }
}

__device__ __forceinline__ int lower_bound_i32(const int* __restrict__ arr, int n, int val) {
    int lo = 0, hi = n;
    while (lo < hi) {
        int mid = (lo + hi) >> 1;
        if (arr[mid] < val) lo = mid + 1; else hi = mid;
    }
    return lo;
}

// K2: per-segment max and sum(exp(s-max)); also record segment bounds
extern "C" __global__ void __launch_bounds__(256)
segstats_kernel(const float* __restrict__ scores, const int* __restrict__ bidx,
                int N, float* __restrict__ seg_max, float* __restrict__ seg_denom,
                int* __restrict__ seg_start)
{
    const int b = blockIdx.x;
    const int lo = lower_bound_i32(bidx, N, b);
    const int hi = lower_bound_i32(bidx, N, b + 1);
    if (threadIdx.x == 0) {
        seg_start[b] = lo;
        if (b == (int)gridDim.x - 1) seg_start[b + 1] = hi;  // == N
    }

    __shared__ float red[256];
    float m = -INFINITY;
    for (int i = lo + threadIdx.x; i < hi; i += 256) m = fmaxf(m, scores[i]);
    red[threadIdx.x] = m;
    __syncthreads();
    #pragma unroll
    for (int off = 128; off > 0; off >>= 1) {
        if (threadIdx.x < off) red[threadIdx.x] = fmaxf(red[threadIdx.x], red[threadIdx.x + off]);
        __syncthreads();
    }
    m = red[0];
    __syncthreads();

    float sum = 0.0f;
    for (int i = lo + threadIdx.x; i < hi; i += 256) sum += __expf(scores[i] - m);
    red[threadIdx.x] = sum;
    __syncthreads();
    #pragma unroll
    for (int off = 128; off > 0; off >>= 1) {
        if (threadIdx.x < off) red[threadIdx.x] += red[threadIdx.x + off];
        __syncthreads();
    }
    if (threadIdx.x == 0) { seg_max[b] = m; seg_denom[b] = red[0]; }
}

// K3: out[b][d] = sum_{i in seg b} (exp(s_i - max_b)/denom_b) * x[i][d]
extern "C" __global__ void __launch_bounds__(128)
weighted_sum_kernel(const float* __restrict__ x, const float* __restrict__ scores,
                    const float* __restrict__ seg_max, const float* __restrict__ seg_denom,
                    const int* __restrict__ seg_start, float* __restrict__ out,
                    int chunks)
{
    const int b = blockIdx.x;
    const int c = blockIdx.y;
    const int lo = seg_start[b], hi = seg_start[b + 1];
    const int len = hi - lo;
    if (len <= 0) return;
    const int per = (len + chunks - 1) / chunks;
    const int s0 = lo + c * per;
    const int s1 = min(hi, s0 + per);
    if (s0 >= s1) return;

    const float m = seg_max[b];
    const float inv_den = 1.0f / seg_denom[b];
    const int d = threadIdx.x;

    float acc = 0.0f;
    #pragma unroll 4
    for (int i = s0; i < s1; ++i) {
        float w = __expf(scores[i] - m) * inv_den;
        acc = fmaf(w, x[(size_t)i * D_DIM + d], acc);
    }
    atomicAdd(&out[b * D_DIM + d], acc);
}

extern "C" void kernel_launch(void* const* d_in, const int* in_sizes, int n_in,
                              void* d_out, int out_size, void* d_ws, size_t ws_size,
                              hipStream_t stream)
{
    const float* x    = (const float*)d_in[0];
    const int*   bidx = (const int*)d_in[1];
    const float* W1   = (const float*)d_in[2];
    const float* b1   = (const float*)d_in[3];
    const float* W2   = (const float*)d_in[4];
    // d_in[5] = b2: cancels in softmax, unused

    const int N = in_sizes[1];
    const int B = out_size / D_DIM;

    float* out = (float*)d_out;
    char* ws = (char*)d_ws;
    float* scores    = (float*)ws;  // N floats
    size_t off = ((size_t)N * sizeof(float) + 255) & ~(size_t)255;
    float* seg_max   = (float*)(ws + off);
    float* seg_denom = seg_max + B;
    int*   seg_start = (int*)(seg_denom + B);  // B+1 ints

    hipMemsetAsync(d_out, 0, (size_t)out_size * sizeof(float), stream);

    const int numTiles = (N + BM - 1) / BM;
    const int grid1 = numTiles < 1024 ? numTiles : 1024;
    scores_mfma_kernel<<<grid1, NTHREADS, 0, stream>>>(x, W1, b1, W2, scores, N, numTiles);
    segstats_kernel<<<B, 256, 0, stream>>>(scores, bidx, N, seg_max, seg_denom, seg_start);
    const int chunks = 8;
    weighted_sum_kernel<<<dim3(B, chunks), 128, 0, stream>>>(
        x, scores, seg_max, seg_denom, seg_start, out, chunks);
}

// Round 4
// 119.528 us; speedup vs baseline: 4.1956x; 2.1105x over previous
//
#include <hip/hip_runtime.h>
#include <math.h>

#define D_DIM 128
#define A_DIM 128
#define BM 128            // rows per block tile
#define NTHREADS 512      // 8 waves

typedef _Float16 f16x8 __attribute__((ext_vector_type(8)));
typedef __attribute__((ext_vector_type(4))) float f32x4;

__device__ __forceinline__ float fast_tanh(float v) {
    float e = __expf(2.0f * v);
    return 1.0f - 2.0f * __builtin_amdgcn_rcpf(e + 1.0f);
}

// K1: scores[i] = sum_a tanh( dot(x_i, W1[:,a]) + b1[a] ) * W2[a]
// fp16 2-term split on A (x = ah + al, each fp16 -> ~22-bit x), W1 single fp16
// (error ~ x*deltaW ~ 7e-5 on the pre-tanh activation). b2 cancels in softmax.
// W1 fp16 in LDS = 32 KB -> 4 blocks/CU by LDS; ~95 live VGPRs -> no spill.
// Register double-buffer: split cur tile -> issue next tile loads -> compute.
extern "C" __global__ void __launch_bounds__(NTHREADS)
scores_mfma_kernel(const float* __restrict__ x,
                   const float* __restrict__ W1,
                   const float* __restrict__ b1,
                   const float* __restrict__ W2,
                   float* __restrict__ scores,
                   int N, int numTiles)
{
    __shared__ _Float16 w1s[A_DIM * D_DIM];   // [col][k], XOR-swizzled, 32 KB
    __shared__ float sB1[A_DIM];
    __shared__ float sW2[A_DIM];

    const int tid = threadIdx.x;
    if (tid < A_DIM) { sB1[tid] = b1[tid]; sW2[tid] = W2[tid]; }

    // stage W1: read coalesced [k][c], write transposed+swizzled fp16
    for (int item = tid; item < A_DIM * 16; item += NTHREADS) {
        const int c = item & (A_DIM - 1);
        const int chunk = item >> 7;          // 16B chunk along k (0..15)
        f16x8 vh;
        #pragma unroll
        for (int j = 0; j < 8; ++j)
            vh[j] = (_Float16)W1[(chunk * 8 + j) * A_DIM + c];
        const int addr = c * 256 + ((chunk ^ (c & 15)) << 4);   // byte offset
        *reinterpret_cast<f16x8*>(reinterpret_cast<char*>(w1s) + addr) = vh;
    }
    __syncthreads();

    const int lane = tid & 63;
    const int wv   = tid >> 6;          // wave -> rows wv*16..wv*16+15
    const int lc   = lane & 15;         // A-row / C-col within 16x16 tile
    const int lg   = lane >> 4;         // 0..3 ; k-group

    float4 buf[8];                      // x row chunk double-buffer (32 VGPR)

    // prologue: load first tile
    {
        const int row  = blockIdx.x * BM + wv * 16 + lc;
        const int rowc = min(row, N - 1);
        const float4* xr = reinterpret_cast<const float4*>(x + (size_t)rowc * D_DIM);
        #pragma unroll
        for (int ks = 0; ks < 4; ++ks) {
            buf[2*ks]   = xr[ks*8 + lg*2];
            buf[2*ks+1] = xr[ks*8 + lg*2 + 1];
        }
    }

    for (int tile = blockIdx.x; tile < numTiles; tile += gridDim.x) {
        // split current buf -> fp16 hi/lo A-fragments (k = ks*32 + lg*8 + j)
        f16x8 ah[4], al[4];
        #pragma unroll
        for (int ks = 0; ks < 4; ++ks) {
            float vv[8] = {buf[2*ks].x, buf[2*ks].y, buf[2*ks].z, buf[2*ks].w,
                           buf[2*ks+1].x, buf[2*ks+1].y, buf[2*ks+1].z, buf[2*ks+1].w};
            #pragma unroll
            for (int j = 0; j < 8; ++j) {
                float xv = vv[j];
                _Float16 h = (_Float16)xv;
                ah[ks][j] = h;
                al[ks][j] = (_Float16)(xv - (float)h);
            }
        }

        // issue next tile's loads; they land in buf during the t-loop
        const int next = tile + gridDim.x;
        if (next < numTiles) {
            const int row  = next * BM + wv * 16 + lc;
            const int rowc = min(row, N - 1);
            const float4* xr = reinterpret_cast<const float4*>(x + (size_t)rowc * D_DIM);
            #pragma unroll
            for (int ks = 0; ks < 4; ++ks) {
                buf[2*ks]   = xr[ks*8 + lg*2];
                buf[2*ks+1] = xr[ks*8 + lg*2 + 1];
            }
        }

        float part0 = 0.f, part1 = 0.f, part2 = 0.f, part3 = 0.f;
        #pragma unroll
        for (int t = 0; t < 8; ++t) {
            f32x4 acc = {0.f, 0.f, 0.f, 0.f};
            const int c = t * 16 + lc;
            const char* base = reinterpret_cast<const char*>(w1s) + c * 256;
            #pragma unroll
            for (int ks = 0; ks < 4; ++ks) {
                const int chunk = ks * 4 + lg;
                f16x8 bh = *reinterpret_cast<const f16x8*>(
                    base + ((chunk ^ (c & 15)) << 4));
                acc = __builtin_amdgcn_mfma_f32_16x16x32_f16(ah[ks], bh, acc, 0, 0, 0);
                acc = __builtin_amdgcn_mfma_f32_16x16x32_f16(al[ks], bh, acc, 0, 0, 0);
            }
            // C layout: col = lane&15 (= c), row = lg*4 + reg
            const float b1v = sB1[c], w2v = sW2[c];
            part0 += fast_tanh(acc[0] + b1v) * w2v;
            part1 += fast_tanh(acc[1] + b1v) * w2v;
            part2 += fast_tanh(acc[2] + b1v) * w2v;
            part3 += fast_tanh(acc[3] + b1v) * w2v;
        }
        // sum over the 16 lc lanes (disjoint col ranges, same rows)
        #pragma unroll
        for (int m = 8; m >= 1; m >>= 1) {
            part0 += __shfl_xor(part0, m);
            part1 += __shfl_xor(part1, m);
            part2 += __shfl_xor(part2, m);
            part3 += __shfl_xor(part3, m);
        }
        if (lc == 0) {
            const int rbase = tile * BM + wv * 16 + lg * 4;
            if (rbase + 0 < N) scores[rbase + 0] = part0;
            if (rbase + 1 < N) scores[rbase + 1] = part1;
            if (rbase + 2 < N) scores[rbase + 2] = part2;
            if (rbase + 3 < N) scores[rbase + 3] = part3;
        }
    }
}

__device__ __forceinline__ int lower_bound_i32(const int* __restrict__ arr, int n, int val) {
    int lo = 0, hi = n;
    while (lo < hi) {
        int mid = (lo + hi) >> 1;
        if (arr[mid] < val) lo = mid + 1; else hi = mid;
    }
    return lo;
}

// K2: per-segment max and sum(exp(s-max)); also record segment bounds
extern "C" __global__ void __launch_bounds__(256)
segstats_kernel(const float* __restrict__ scores, const int* __restrict__ bidx,
                int N, float* __restrict__ seg_max, float* __restrict__ seg_denom,
                int* __restrict__ seg_start)
{
    const int b = blockIdx.x;
    const int lo = lower_bound_i32(bidx, N, b);
    const int hi = lower_bound_i32(bidx, N, b + 1);
    if (threadIdx.x == 0) {
        seg_start[b] = lo;
        if (b == (int)gridDim.x - 1) seg_start[b + 1] = hi;  // == N
    }

    __shared__ float red[256];
    float m = -INFINITY;
    for (int i = lo + threadIdx.x; i < hi; i += 256) m = fmaxf(m, scores[i]);
    red[threadIdx.x] = m;
    __syncthreads();
    #pragma unroll
    for (int off = 128; off > 0; off >>= 1) {
        if (threadIdx.x < off) red[threadIdx.x] = fmaxf(red[threadIdx.x], red[threadIdx.x + off]);
        __syncthreads();
    }
    m = red[0];
    __syncthreads();

    float sum = 0.0f;
    for (int i = lo + threadIdx.x; i < hi; i += 256) sum += __expf(scores[i] - m);
    red[threadIdx.x] = sum;
    __syncthreads();
    #pragma unroll
    for (int off = 128; off > 0; off >>= 1) {
        if (threadIdx.x < off) red[threadIdx.x] += red[threadIdx.x + off];
        __syncthreads();
    }
    if (threadIdx.x == 0) { seg_max[b] = m; seg_denom[b] = red[0]; }
}

// K3: out[b][d] = sum_{i in seg b} (exp(s_i - max_b)/denom_b) * x[i][d]
extern "C" __global__ void __launch_bounds__(128)
weighted_sum_kernel(const float* __restrict__ x, const float* __restrict__ scores,
                    const float* __restrict__ seg_max, const float* __restrict__ seg_denom,
                    const int* __restrict__ seg_start, float* __restrict__ out,
                    int chunks)
{
    const int b = blockIdx.x;
    const int c = blockIdx.y;
    const int lo = seg_start[b], hi = seg_start[b + 1];
    const int len = hi - lo;
    if (len <= 0) return;
    const int per = (len + chunks - 1) / chunks;
    const int s0 = lo + c * per;
    const int s1 = min(hi, s0 + per);
    if (s0 >= s1) return;

    const float m = seg_max[b];
    const float inv_den = 1.0f / seg_denom[b];
    const int d = threadIdx.x;

    float acc = 0.0f;
    #pragma unroll 4
    for (int i = s0; i < s1; ++i) {
        float w = __expf(scores[i] - m) * inv_den;
        acc = fmaf(w, x[(size_t)i * D_DIM + d], acc);
    }
    atomicAdd(&out[b * D_DIM + d], acc);
}

extern "C" void kernel_launch(void* const* d_in, const int* in_sizes, int n_in,
                              void* d_out, int out_size, void* d_ws, size_t ws_size,
                              hipStream_t stream)
{
    const float* x    = (const float*)d_in[0];
    const int*   bidx = (const int*)d_in[1];
    const float* W1   = (const float*)d_in[2];
    const float* b1   = (const float*)d_in[3];
    const float* W2   = (const float*)d_in[4];
    // d_in[5] = b2: cancels in softmax, unused

    const int N = in_sizes[1];
    const int B = out_size / D_DIM;

    float* out = (float*)d_out;
    char* ws = (char*)d_ws;
    float* scores    = (float*)ws;  // N floats
    size_t off = ((size_t)N * sizeof(float) + 255) & ~(size_t)255;
    float* seg_max   = (float*)(ws + off);
    float* seg_denom = seg_max + B;
    int*   seg_start = (int*)(seg_denom + B);  // B+1 ints

    hipMemsetAsync(d_out, 0, (size_t)out_size * sizeof(float), stream);

    const int numTiles = (N + BM - 1) / BM;
    const int grid1 = numTiles < 1024 ? numTiles : 1024;
    scores_mfma_kernel<<<grid1, NTHREADS, 0, stream>>>(x, W1, b1, W2, scores, N, numTiles);
    segstats_kernel<<<B, 256, 0, stream>>>(scores, bidx, N, seg_max, seg_denom, seg_start);
    const int chunks = 8;
    weighted_sum_kernel<<<dim3(B, chunks), 128, 0, stream>>>(
        x, scores, seg_max, seg_denom, seg_start, out, chunks);
}

// Round 5
// 82.595 us; speedup vs baseline: 6.0717x; 1.4472x over previous
//
#include <hip/hip_runtime.h>
#include <math.h>

#define D_DIM 128
#define A_DIM 128
#define NTHREADS 512      // 8 waves; one block per segment

typedef _Float16 f16x8 __attribute__((ext_vector_type(8)));
typedef __attribute__((ext_vector_type(4))) float f32x4;

__device__ __forceinline__ float fast_tanh(float v) {
    float e = __expf(2.0f * v);
    return 1.0f - 2.0f * __builtin_amdgcn_rcpf(e + 1.0f);
}

__device__ __forceinline__ int lower_bound_i32(const int* __restrict__ arr, int n, int val) {
    int lo = 0, hi = n;
    while (lo < hi) {
        int mid = (lo + hi) >> 1;
        if (arr[mid] < val) lo = mid + 1; else hi = mid;
    }
    return lo;
}

// Fully fused: per-segment block, online-softmax over 128-row tiles.
// scores via fp16 2-term-split MFMA (x = ah+al fp16 exact to ~2^-22, W1 fp16);
// b2 cancels in softmax. x is read from HBM exactly once.
extern "C" __global__ void __launch_bounds__(NTHREADS)
fused_attn_kernel(const float* __restrict__ x,
                  const int* __restrict__ bidx,
                  const float* __restrict__ W1,
                  const float* __restrict__ b1,
                  const float* __restrict__ W2,
                  float* __restrict__ out,
                  int N, int B)
{
    __shared__ _Float16 w1s[A_DIM * D_DIM];   // 32 KB, [col][k] XOR-swizzled
    __shared__ float sB1[A_DIM];
    __shared__ float sW2[A_DIM];
    __shared__ float s_lds[128];              // per-tile scores
    __shared__ float o_red[8 * 4 * 32];       // 4 KB epilogue reduce
    __shared__ int   seg_bounds[2];

    const int tid = threadIdx.x;
    const int b   = blockIdx.x;

    if (tid == 0) {
        seg_bounds[0] = lower_bound_i32(bidx, N, b);
        seg_bounds[1] = lower_bound_i32(bidx, N, b + 1);
    }
    if (tid < A_DIM) { sB1[tid] = b1[tid]; sW2[tid] = W2[tid]; }

    // stage W1: read coalesced [k][c], write transposed+swizzled fp16
    for (int item = tid; item < A_DIM * 16; item += NTHREADS) {
        const int c = item & (A_DIM - 1);
        const int chunk = item >> 7;          // 16B chunk along k (0..15)
        f16x8 vh;
        #pragma unroll
        for (int j = 0; j < 8; ++j)
            vh[j] = (_Float16)W1[(chunk * 8 + j) * A_DIM + c];
        const int addr = c * 256 + ((chunk ^ (c & 15)) << 4);
        *reinterpret_cast<f16x8*>(reinterpret_cast<char*>(w1s) + addr) = vh;
    }
    __syncthreads();

    const int lo = seg_bounds[0], hi = seg_bounds[1];
    const int len = hi - lo;

    if (len <= 0) {                           // empty segment -> zeros
        if (tid < D_DIM) out[b * D_DIM + tid] = 0.0f;
        return;
    }

    const int lane = tid & 63;
    const int wv   = tid >> 6;          // wave -> local rows wv*16..wv*16+15
    const int lc   = lane & 15;         // A-row within 16x16 tile
    const int lg   = lane >> 4;         // 0..3 ; k-group
    const int nt   = (len + 127) >> 7;  // tiles of 128 rows

    float m = -INFINITY;                // running max (identical across block)
    float denom = 0.0f;                 // running sum-exp (identical)
    float o_part[32];                   // running weighted x, dims ks*32+lg*8+j
    #pragma unroll
    for (int v = 0; v < 32; ++v) o_part[v] = 0.0f;

    float4 buf[8];
    {   // prologue: load tile 0 (this thread's row = lo + wv*16 + lc)
        const int gi = min(lo + wv * 16 + lc, N - 1);
        const float4* xr = reinterpret_cast<const float4*>(x + (size_t)gi * D_DIM);
        #pragma unroll
        for (int ks = 0; ks < 4; ++ks) {
            buf[2*ks]   = xr[ks*8 + lg*2];
            buf[2*ks+1] = xr[ks*8 + lg*2 + 1];
        }
    }

    for (int tile = 0; tile < nt; ++tile) {
        // split current buf into fp16 hi/lo fragments (k = ks*32 + lg*8 + j)
        f16x8 ah[4], al[4];
        #pragma unroll
        for (int ks = 0; ks < 4; ++ks) {
            float vv[8] = {buf[2*ks].x, buf[2*ks].y, buf[2*ks].z, buf[2*ks].w,
                           buf[2*ks+1].x, buf[2*ks+1].y, buf[2*ks+1].z, buf[2*ks+1].w};
            #pragma unroll
            for (int j = 0; j < 8; ++j) {
                float xv = vv[j];
                _Float16 h = (_Float16)xv;
                ah[ks][j] = h;
                al[ks][j] = (_Float16)(xv - (float)h);
            }
        }

        // prefetch next tile while we compute
        if (tile + 1 < nt) {
            const int gi = min(lo + (tile + 1) * 128 + wv * 16 + lc, N - 1);
            const float4* xr = reinterpret_cast<const float4*>(x + (size_t)gi * D_DIM);
            #pragma unroll
            for (int ks = 0; ks < 4; ++ks) {
                buf[2*ks]   = xr[ks*8 + lg*2];
                buf[2*ks+1] = xr[ks*8 + lg*2 + 1];
            }
        }

        // ---- scores via MFMA ----
        float part0 = 0.f, part1 = 0.f, part2 = 0.f, part3 = 0.f;
        #pragma unroll
        for (int t = 0; t < 8; ++t) {
            f32x4 acc = {0.f, 0.f, 0.f, 0.f};
            const int c = t * 16 + lc;
            const char* base = reinterpret_cast<const char*>(w1s) + c * 256;
            #pragma unroll
            for (int ks = 0; ks < 4; ++ks) {
                const int chunk = ks * 4 + lg;
                f16x8 bh = *reinterpret_cast<const f16x8*>(
                    base + ((chunk ^ (c & 15)) << 4));
                acc = __builtin_amdgcn_mfma_f32_16x16x32_f16(ah[ks], bh, acc, 0, 0, 0);
                acc = __builtin_amdgcn_mfma_f32_16x16x32_f16(al[ks], bh, acc, 0, 0, 0);
            }
            const float b1v = sB1[c], w2v = sW2[c];
            part0 += fast_tanh(acc[0] + b1v) * w2v;
            part1 += fast_tanh(acc[1] + b1v) * w2v;
            part2 += fast_tanh(acc[2] + b1v) * w2v;
            part3 += fast_tanh(acc[3] + b1v) * w2v;
        }
        #pragma unroll
        for (int mk = 8; mk >= 1; mk >>= 1) {
            part0 += __shfl_xor(part0, mk);
            part1 += __shfl_xor(part1, mk);
            part2 += __shfl_xor(part2, mk);
            part3 += __shfl_xor(part3, mk);
        }
        if (lc == 0) {
            const int rb = wv * 16 + lg * 4;       // local row base
            const int gbase = tile * 128 + rb;     // row within segment
            s_lds[rb + 0] = (gbase + 0 < len) ? part0 : -INFINITY;
            s_lds[rb + 1] = (gbase + 1 < len) ? part1 : -INFINITY;
            s_lds[rb + 2] = (gbase + 2 < len) ? part2 : -INFINITY;
            s_lds[rb + 3] = (gbase + 3 < len) ? part3 : -INFINITY;
        }
        __syncthreads();

        // ---- online softmax update (all waves redundantly, identical) ----
        const float a0 = s_lds[lane], a1 = s_lds[64 + lane];
        float pm = fmaxf(a0, a1);
        #pragma unroll
        for (int mk = 32; mk >= 1; mk >>= 1) pm = fmaxf(pm, __shfl_xor(pm, mk));
        const float mn = fmaxf(m, pm);
        const float f  = __expf(m - mn);           // first tile: exp(-inf)=0
        float ds = __expf(a0 - mn) + __expf(a1 - mn);
        #pragma unroll
        for (int mk = 32; mk >= 1; mk >>= 1) ds += __shfl_xor(ds, mk);
        denom = denom * f + ds;
        m = mn;

        // ---- accumulate weighted x from the fragments already in regs ----
        const float w = __expf(s_lds[wv * 16 + lc] - mn);  // this thread's row
        #pragma unroll
        for (int ks = 0; ks < 4; ++ks) {
            #pragma unroll
            for (int j = 0; j < 8; ++j) {
                const int v = ks * 8 + j;
                o_part[v] = fmaf(o_part[v], f,
                                 w * ((float)ah[ks][j] + (float)al[ks][j]));
            }
        }
        __syncthreads();   // protect s_lds before next tile overwrites
    }

    // ---- epilogue: reduce o_part over the 16 lc-lanes, then over waves ----
    #pragma unroll
    for (int v = 0; v < 32; ++v) {
        #pragma unroll
        for (int mk = 8; mk >= 1; mk >>= 1)
            o_part[v] += __shfl_xor(o_part[v], mk);
    }
    if (lc == 0) {
        #pragma unroll
        for (int v = 0; v < 32; ++v)
            o_red[(wv * 4 + lg) * 32 + v] = o_part[v];
    }
    __syncthreads();
    if (tid < 128) {
        const int lg2 = tid >> 5, v = tid & 31;
        float s = 0.0f;
        #pragma unroll
        for (int w2 = 0; w2 < 8; ++w2) s += o_red[(w2 * 4 + lg2) * 32 + v];
        const int d = (v >> 3) * 32 + lg2 * 8 + (v & 7);
        out[b * D_DIM + d] = s / denom;
    }
}

extern "C" void kernel_launch(void* const* d_in, const int* in_sizes, int n_in,
                              void* d_out, int out_size, void* d_ws, size_t ws_size,
                              hipStream_t stream)
{
    const float* x    = (const float*)d_in[0];
    const int*   bidx = (const int*)d_in[1];
    const float* W1   = (const float*)d_in[2];
    const float* b1   = (const float*)d_in[3];
    const float* W2   = (const float*)d_in[4];
    // d_in[5] = b2: cancels in softmax, unused

    const int N = in_sizes[1];
    const int B = out_size / D_DIM;

    fused_attn_kernel<<<B, NTHREADS, 0, stream>>>(
        x, bidx, W1, b1, W2, (float*)d_out, N, B);
}